// Round 1
// baseline (464.016 us; speedup 1.0000x reference)
//
#include <hip/hip_runtime.h>

#define BB   16
#define NN   4096
#define SS   1024
#define D1C  128
#define D2C  256
#define CIN  384
#define CO   128
#define MM   (BB*NN)   // 65536 rows

// ---------------- generic small weight transpose: src[R][C] -> dst[C][R] ----------------
__global__ __launch_bounds__(256) void transpose_k(const float* __restrict__ src,
                                                   float* __restrict__ dst, int R, int C) {
  int i = blockIdx.x * 256 + threadIdx.x;
  if (i < R * C) {
    int r = i / C, c = i - r * C;
    dst[(size_t)c * R + r] = src[i];
  }
}

// ---------------- top-3 nearest neighbors + interpolation weights ----------------
__global__ __launch_bounds__(256) void top3_kernel(const float* __restrict__ xyz1,
                                                   const float* __restrict__ xyz2,
                                                   int* __restrict__ idx3,
                                                   float* __restrict__ w3) {
  __shared__ float sx[SS], sy[SS], sz[SS], snn[SS];
  int b = blockIdx.x >> 4;                       // 16 blocks of 256 threads per batch
  int n = ((blockIdx.x & 15) << 8) | threadIdx.x;
  const float* x2 = xyz2 + (size_t)b * SS * 3;
  for (int i = threadIdx.x; i < SS; i += 256) {
    float a = x2[i*3+0], c = x2[i*3+1], d = x2[i*3+2];
    sx[i] = a; sy[i] = c; sz[i] = d; snn[i] = a*a + c*c + d*d;
  }
  __syncthreads();
  size_t gm = (size_t)b * NN + n;
  float px = xyz1[gm*3+0], py = xyz1[gm*3+1], pz = xyz1[gm*3+2];
  float n1 = px*px + py*py + pz*pz;
  float d0 = 3.4e38f, d1 = 3.4e38f, d2 = 3.4e38f;
  int   i0 = 0, i1 = 0, i2 = 0;
  for (int s = 0; s < SS; ++s) {
    float d = n1 + snn[s] - 2.0f * (px*sx[s] + py*sy[s] + pz*sz[s]);
    if (d < d2) {                   // strict < keeps earliest index on ties (top_k semantics)
      if (d < d1) {
        if (d < d0) { d2=d1; i2=i1; d1=d0; i1=i0; d0=d; i0=s; }
        else        { d2=d1; i2=i1; d1=d;  i1=s; }
      } else        { d2=d;  i2=s; }
    }
  }
  float r0 = 1.0f/(d0 + 1e-8f), r1 = 1.0f/(d1 + 1e-8f), r2 = 1.0f/(d2 + 1e-8f);
  float inv = 1.0f/(r0 + r1 + r2);
  idx3[gm*3+0] = i0; idx3[gm*3+1] = i1; idx3[gm*3+2] = i2;
  w3  [gm*3+0] = r0*inv; w3[gm*3+1] = r1*inv; w3[gm*3+2] = r2*inv;
}

// ---------------- GEMM1: feats(65536x384) @ fuse_wT(384x128) + bias, write pre-BN [128][M], stats ----------------
// feats cols 0..127  = points1[b][c][n]   (direct, coalesced)
// feats cols 128..383 = sum_j w3[m][j] * points2[b][c-128][idx3[m][j]]  (fused gather)
__global__ __launch_bounds__(256) void gemm1_kernel(
    const float* __restrict__ p1, const float* __restrict__ p2,
    const int* __restrict__ idx3, const float* __restrict__ w3,
    const float* __restrict__ wT, const float* __restrict__ bias,
    float* __restrict__ outb, float* __restrict__ gsum, float* __restrict__ gssq) {
  __shared__ float As[32][128];
  __shared__ float Ws[32][128];
  __shared__ int   sI[384];
  __shared__ float sWt[384];
  __shared__ float sSum[128], sSsq[128];
  int t  = threadIdx.x;
  int m0 = blockIdx.x * 128;
  int b  = m0 >> 12;          // 4096 rows per batch, 128 | 4096
  int n0 = m0 & (NN - 1);
  for (int i = t; i < 384; i += 256) { sI[i] = idx3[(size_t)m0*3 + i]; sWt[i] = w3[(size_t)m0*3 + i]; }
  if (t < 128) { sSum[t] = 0.f; sSsq[t] = 0.f; }
  __syncthreads();
  int ty = t >> 4, tx = t & 15;
  int ra = ty * 4, ca = tx * 4;   // rows {ra..ra+3, 64+ra..}, cols {ca..ca+3, 64+ca..}
  float acc[8][8]{};
  for (int kt = 0; kt < 12; ++kt) {
    int c0 = kt * 32;
    if (c0 < 128) {
      const float* src = p1 + ((size_t)b * D1C + c0) * NN + n0;
      #pragma unroll
      for (int e = 0; e < 4; ++e) {
        int k = e*8 + (t >> 5);
        int m = (t & 31) * 4;
        *(float4*)&As[k][m] = *(const float4*)(src + (size_t)k * NN + m);
      }
    } else {
      const float* srcb = p2 + (size_t)b * D2C * SS + (size_t)(c0 - 128) * SS;
      #pragma unroll
      for (int e = 0; e < 16; ++e) {
        int lin = e*256 + t;
        int k = lin >> 7, m = lin & 127;
        const float* row = srcb + (size_t)k * SS;
        float v = sWt[m*3+0] * row[sI[m*3+0]]
                + sWt[m*3+1] * row[sI[m*3+1]]
                + sWt[m*3+2] * row[sI[m*3+2]];
        As[k][m] = v;
      }
    }
    #pragma unroll
    for (int e = 0; e < 4; ++e) {
      int k = e*8 + (t >> 5);
      int o = (t & 31) * 4;
      *(float4*)&Ws[k][o] = *(const float4*)(wT + (size_t)(c0 + k) * CO + o);
    }
    __syncthreads();
    #pragma unroll 8
    for (int k = 0; k < 32; ++k) {
      float4 a0 = *(const float4*)&As[k][ra];
      float4 a1 = *(const float4*)&As[k][ra + 64];
      float4 b0 = *(const float4*)&Ws[k][ca];
      float4 b1 = *(const float4*)&Ws[k][ca + 64];
      float av[8] = {a0.x,a0.y,a0.z,a0.w,a1.x,a1.y,a1.z,a1.w};
      float bv[8] = {b0.x,b0.y,b0.z,b0.w,b1.x,b1.y,b1.z,b1.w};
      #pragma unroll
      for (int i = 0; i < 8; ++i)
        #pragma unroll
        for (int j = 0; j < 8; ++j)
          acc[i][j] = fmaf(av[i], bv[j], acc[i][j]);
    }
    __syncthreads();
  }
  #pragma unroll
  for (int j = 0; j < 8; ++j) {
    int o = (j < 4) ? (ca + j) : (64 + ca + j - 4);
    float bj = bias[o];
    float s = 0.f, q = 0.f;
    #pragma unroll
    for (int i = 0; i < 8; ++i) { float v = acc[i][j] + bj; acc[i][j] = v; s += v; q += v*v; }
    atomicAdd(&sSum[o], s);
    atomicAdd(&sSsq[o], q);
    float* dst = outb + (size_t)o * MM + m0;
    float4 v0 = make_float4(acc[0][j], acc[1][j], acc[2][j], acc[3][j]);
    float4 v1 = make_float4(acc[4][j], acc[5][j], acc[6][j], acc[7][j]);
    *(float4*)(dst + ra)      = v0;
    *(float4*)(dst + 64 + ra) = v1;
  }
  __syncthreads();
  if (t < 128) { atomicAdd(&gsum[t], sSum[t]); atomicAdd(&gssq[t], sSsq[t]); }
}

// ---------------- GEMM2/3: A = relu(bn(in[128][M])) @ wT(128x128) + bias -> out[128][M] (in-place safe), stats ----------------
__global__ __launch_bounds__(256) void gemm23_kernel(
    const float* inb, const float* __restrict__ scale, const float* __restrict__ shift,
    const float* __restrict__ wT, const float* __restrict__ bias,
    float* outb, float* __restrict__ gsum, float* __restrict__ gssq) {
  __shared__ float As[32][128];
  __shared__ float Ws[32][128];
  __shared__ float sSum[128], sSsq[128];
  int t  = threadIdx.x;
  int m0 = blockIdx.x * 128;
  if (t < 128) { sSum[t] = 0.f; sSsq[t] = 0.f; }
  int ty = t >> 4, tx = t & 15;
  int ra = ty * 4, ca = tx * 4;
  float acc[8][8]{};
  for (int kt = 0; kt < 4; ++kt) {
    int c0 = kt * 32;
    #pragma unroll
    for (int e = 0; e < 4; ++e) {
      int k = e*8 + (t >> 5);
      int m = (t & 31) * 4;
      int c = c0 + k;
      float4 v = *(const float4*)(inb + (size_t)c * MM + m0 + m);
      float sc = scale[c], sh = shift[c];
      v.x = fmaxf(fmaf(v.x, sc, sh), 0.f);
      v.y = fmaxf(fmaf(v.y, sc, sh), 0.f);
      v.z = fmaxf(fmaf(v.z, sc, sh), 0.f);
      v.w = fmaxf(fmaf(v.w, sc, sh), 0.f);
      *(float4*)&As[k][m] = v;
    }
    #pragma unroll
    for (int e = 0; e < 4; ++e) {
      int k = e*8 + (t >> 5);
      int o = (t & 31) * 4;
      *(float4*)&Ws[k][o] = *(const float4*)(wT + (size_t)(c0 + k) * CO + o);
    }
    __syncthreads();
    #pragma unroll 8
    for (int k = 0; k < 32; ++k) {
      float4 a0 = *(const float4*)&As[k][ra];
      float4 a1 = *(const float4*)&As[k][ra + 64];
      float4 b0 = *(const float4*)&Ws[k][ca];
      float4 b1 = *(const float4*)&Ws[k][ca + 64];
      float av[8] = {a0.x,a0.y,a0.z,a0.w,a1.x,a1.y,a1.z,a1.w};
      float bv[8] = {b0.x,b0.y,b0.z,b0.w,b1.x,b1.y,b1.z,b1.w};
      #pragma unroll
      for (int i = 0; i < 8; ++i)
        #pragma unroll
        for (int j = 0; j < 8; ++j)
          acc[i][j] = fmaf(av[i], bv[j], acc[i][j]);
    }
    __syncthreads();
  }
  #pragma unroll
  for (int j = 0; j < 8; ++j) {
    int o = (j < 4) ? (ca + j) : (64 + ca + j - 4);
    float bj = bias[o];
    float s = 0.f, q = 0.f;
    #pragma unroll
    for (int i = 0; i < 8; ++i) { float v = acc[i][j] + bj; acc[i][j] = v; s += v; q += v*v; }
    atomicAdd(&sSum[o], s);
    atomicAdd(&sSsq[o], q);
    float* dst = outb + (size_t)o * MM + m0;
    float4 v0 = make_float4(acc[0][j], acc[1][j], acc[2][j], acc[3][j]);
    float4 v1 = make_float4(acc[4][j], acc[5][j], acc[6][j], acc[7][j]);
    *(float4*)(dst + ra)      = v0;
    *(float4*)(dst + 64 + ra) = v1;
  }
  __syncthreads();
  if (t < 128) { atomicAdd(&gsum[t], sSum[t]); atomicAdd(&gssq[t], sSsq[t]); }
}

// ---------------- finalize BN stats -> scale/shift ----------------
__global__ void finalize_bn(const float* __restrict__ gsum, const float* __restrict__ gssq,
                            const float* __restrict__ g, const float* __restrict__ be,
                            float* __restrict__ scale, float* __restrict__ shift) {
  int c = threadIdx.x;
  const float invM = 1.0f / (float)MM;
  float mean = gsum[c] * invM;
  float var  = gssq[c] * invM - mean * mean;
  float rstd = rsqrtf(var + 1e-5f);
  float sc   = g[c] * rstd;
  scale[c] = sc;
  shift[c] = fmaf(-mean, sc, be[c]);
}

// ---------------- final: out[b][o][n] = relu(bn2(h2) + relu(bn0(x))) ----------------
__global__ __launch_bounds__(256) void final_kernel(
    const float* __restrict__ bufX, const float* __restrict__ bufH,
    const float* __restrict__ bnp, float* __restrict__ out) {
  int lin = blockIdx.x * 256 + threadIdx.x;     // over [128][M/4]
  int o = lin >> 14;                            // M/4 = 16384
  int r = lin & 16383;
  int m = r * 4;
  int b = m >> 12;
  int n = m & (NN - 1);
  float s0 = bnp[o], t0 = bnp[128 + o], s2 = bnp[512 + o], t2 = bnp[640 + o];
  float4 x = *(const float4*)(bufX + (size_t)o * MM + m);
  float4 h = *(const float4*)(bufH + (size_t)o * MM + m);
  float4 y;
  y.x = fmaxf(fmaf(h.x, s2, t2) + fmaxf(fmaf(x.x, s0, t0), 0.f), 0.f);
  y.y = fmaxf(fmaf(h.y, s2, t2) + fmaxf(fmaf(x.y, s0, t0), 0.f), 0.f);
  y.z = fmaxf(fmaf(h.z, s2, t2) + fmaxf(fmaf(x.z, s0, t0), 0.f), 0.f);
  y.w = fmaxf(fmaf(h.w, s2, t2) + fmaxf(fmaf(x.w, s0, t0), 0.f), 0.f);
  *(float4*)(out + (size_t)b * CO * NN + (size_t)o * NN + n) = y;
}

extern "C" void kernel_launch(void* const* d_in, const int* in_sizes, int n_in,
                              void* d_out, int out_size, void* d_ws, size_t ws_size,
                              hipStream_t stream) {
  const float* xyz1    = (const float*)d_in[0];
  const float* xyz2    = (const float*)d_in[1];
  const float* points1 = (const float*)d_in[2];
  const float* points2 = (const float*)d_in[3];
  const float* fuse_w  = (const float*)d_in[4];
  const float* fuse_b  = (const float*)d_in[5];
  const float* fuse_g  = (const float*)d_in[6];
  const float* fuse_be = (const float*)d_in[7];
  const float* w1      = (const float*)d_in[8];
  const float* b1      = (const float*)d_in[9];
  const float* g1      = (const float*)d_in[10];
  const float* be1     = (const float*)d_in[11];
  const float* w2      = (const float*)d_in[12];
  const float* b2      = (const float*)d_in[13];
  const float* g2      = (const float*)d_in[14];
  const float* be2     = (const float*)d_in[15];

  char* ws = (char*)d_ws;
  size_t off = 0;
  auto alloc = [&](size_t bytes) -> void* {
    void* p = ws + off;
    off += (bytes + 255) & ~(size_t)255;
    return p;
  };
  int*   idx3  = (int*)  alloc((size_t)MM * 3 * 4);
  float* w3    = (float*)alloc((size_t)MM * 3 * 4);
  float* wT0   = (float*)alloc((size_t)CIN * CO * 4);
  float* wT1   = (float*)alloc((size_t)CO * CO * 4);
  float* wT2   = (float*)alloc((size_t)CO * CO * 4);
  float* stats = (float*)alloc(6 * 128 * 4);  // gsum0,gssq0,gsum1,gssq1,gsum2,gssq2
  float* bnp   = (float*)alloc(6 * 128 * 4);  // scale0,shift0,scale1,shift1,scale2,shift2
  float* bufX  = (float*)alloc((size_t)MM * CO * 4);
  float* bufH  = (float*)alloc((size_t)MM * CO * 4);
  if (off > ws_size) return;  // workspace too small: signature = untouched output

  hipMemsetAsync(stats, 0, 6 * 128 * 4, stream);
  transpose_k<<<(CO*CIN + 255)/256, 256, 0, stream>>>(fuse_w, wT0, CO, CIN);
  transpose_k<<<(CO*CO  + 255)/256, 256, 0, stream>>>(w1,     wT1, CO, CO);
  transpose_k<<<(CO*CO  + 255)/256, 256, 0, stream>>>(w2,     wT2, CO, CO);
  top3_kernel<<<BB * (NN/256), 256, 0, stream>>>(xyz1, xyz2, idx3, w3);

  gemm1_kernel<<<MM/128, 256, 0, stream>>>(points1, points2, idx3, w3, wT0, fuse_b,
                                           bufX, stats + 0, stats + 128);
  finalize_bn<<<1, 128, 0, stream>>>(stats + 0, stats + 128, fuse_g, fuse_be, bnp + 0, bnp + 128);

  gemm23_kernel<<<MM/128, 256, 0, stream>>>(bufX, bnp + 0, bnp + 128, wT1, b1,
                                            bufH, stats + 256, stats + 384);
  finalize_bn<<<1, 128, 0, stream>>>(stats + 256, stats + 384, g1, be1, bnp + 256, bnp + 384);

  gemm23_kernel<<<MM/128, 256, 0, stream>>>(bufH, bnp + 256, bnp + 384, wT2, b2,
                                            bufH, stats + 512, stats + 640);
  finalize_bn<<<1, 128, 0, stream>>>(stats + 512, stats + 640, g2, be2, bnp + 512, bnp + 640);

  final_kernel<<<(CO * (MM/4)) / 256, 256, 0, stream>>>(bufX, bufH, bnp, (float*)d_out);
}

// Round 2
// 439.923 us; speedup vs baseline: 1.0548x; 1.0548x over previous
//
#include <hip/hip_runtime.h>

#define BB   16
#define NN   4096
#define SS   1024
#define D1C  128
#define D2C  256
#define CIN  384
#define CO   128
#define MM   (BB*NN)   // 65536 rows

typedef __attribute__((ext_vector_type(8))) short short8;
typedef __attribute__((ext_vector_type(4))) float f32x4;

__device__ __forceinline__ short f2bf(float f) {
  unsigned u = __builtin_bit_cast(unsigned, f);
  u += 0x7fffu + ((u >> 16) & 1u);           // RNE
  return (short)(u >> 16);
}

// ---------------- arrange weights into per-lane MFMA A-fragments ----------------
// wf[(kt*8+ob)*64+lane] = 8 bf16 of W[o=ob*16+(lane&15)][k=kt*32+(lane>>4)*8 .. +7]
__global__ __launch_bounds__(64) void arrange_w(const float* __restrict__ w,
                                                uint4* __restrict__ wf, int K) {
  int id = blockIdx.x * 64 + threadIdx.x;
  int lane = id & 63;
  int ob = (id >> 6) & 7;
  int kt = id >> 9;
  int o = ob * 16 + (lane & 15);
  int k = kt * 32 + (lane >> 4) * 8;
  const float* src = w + (size_t)o * K + k;
  union { ushort u[8]; uint4 v; } p;
  #pragma unroll
  for (int j = 0; j < 8; ++j) p.u[j] = (ushort)f2bf(src[j]);
  wf[id] = p.v;
}

// ---------------- top-3 nearest neighbors + interpolation weights ----------------
__global__ __launch_bounds__(256) void top3_kernel(const float* __restrict__ xyz1,
                                                   const float* __restrict__ xyz2,
                                                   int* __restrict__ idx3,
                                                   float* __restrict__ w3) {
  __shared__ float sx[SS], sy[SS], sz[SS], snn[SS];
  int b = blockIdx.x >> 4;
  int n = ((blockIdx.x & 15) << 8) | threadIdx.x;
  const float* x2 = xyz2 + (size_t)b * SS * 3;
  for (int i = threadIdx.x; i < SS; i += 256) {
    float a = x2[i*3+0], c = x2[i*3+1], d = x2[i*3+2];
    sx[i] = a; sy[i] = c; sz[i] = d; snn[i] = a*a + c*c + d*d;
  }
  __syncthreads();
  size_t gm = (size_t)b * NN + n;
  float px = xyz1[gm*3+0], py = xyz1[gm*3+1], pz = xyz1[gm*3+2];
  float n1 = px*px + py*py + pz*pz;
  float d0 = 3.4e38f, d1 = 3.4e38f, d2 = 3.4e38f;
  int   i0 = 0, i1 = 0, i2 = 0;
  for (int s = 0; s < SS; ++s) {
    float d = n1 + snn[s] - 2.0f * (px*sx[s] + py*sy[s] + pz*sz[s]);
    if (d < d2) {
      if (d < d1) {
        if (d < d0) { d2=d1; i2=i1; d1=d0; i1=i0; d0=d; i0=s; }
        else        { d2=d1; i2=i1; d1=d;  i1=s; }
      } else        { d2=d;  i2=s; }
    }
  }
  float r0 = 1.0f/(d0 + 1e-8f), r1 = 1.0f/(d1 + 1e-8f), r2 = 1.0f/(d2 + 1e-8f);
  float inv = 1.0f/(r0 + r1 + r2);
  idx3[gm*3+0] = i0; idx3[gm*3+1] = i1; idx3[gm*3+2] = i2;
  w3  [gm*3+0] = r0*inv; w3[gm*3+1] = r1*inv; w3[gm*3+2] = r2*inv;
}

// ---------------- GEMM1 (MFMA): C[o][m] = sum_k W[o][k]*feats[k][m] + bias ----------------
// feats k<128 from points1 (direct), k>=128 from 3-NN gather of points2.
// wave: D-tile 128(o) x 16(m); block: 4 waves => m-tile 64; grid 1024.
__global__ __launch_bounds__(256, 4) void gemm1_mfma(
    const float* __restrict__ p1, const float* __restrict__ p2,
    const int* __restrict__ idx3, const float* __restrict__ w3,
    const uint4* __restrict__ wfrag, const float* __restrict__ bias,
    float* __restrict__ outb) {
  int t = threadIdx.x;
  int wid = t >> 6, lane = t & 63;
  int bid = blockIdx.x;
  bid = (bid & 7) * 128 + (bid >> 3);          // XCD-chunked swizzle (1024 % 8 == 0)
  int m0 = bid * 64 + wid * 16;
  int b  = m0 >> 12;
  int cl = lane & 15, g = lane >> 4;
  int m  = m0 + cl;
  int n  = m & (NN - 1);
  int i0 = idx3[m*3+0], i1 = idx3[m*3+1], i2 = idx3[m*3+2];
  float wA = w3[m*3+0], wB = w3[m*3+1], wC = w3[m*3+2];
  const float* p2b = p2 + (size_t)b * D2C * SS;
  const float* p1b = p1 + (size_t)b * D1C * NN + n;
  f32x4 acc[8] = {};
  for (int kt = 0; kt < 12; ++kt) {
    int kbase = kt * 32 + g * 8;
    float xv[8];
    if (kt < 4) {
      #pragma unroll
      for (int j = 0; j < 8; ++j) xv[j] = p1b[(size_t)(kbase + j) * NN];
    } else {
      const float* row = p2b + (size_t)(kbase - 128) * SS;
      #pragma unroll
      for (int j = 0; j < 8; ++j) {
        const float* r = row + (size_t)j * SS;
        xv[j] = wA * r[i0] + wB * r[i1] + wC * r[i2];
      }
    }
    short8 bv;
    #pragma unroll
    for (int j = 0; j < 8; ++j) bv[j] = f2bf(xv[j]);
    const uint4* wk = wfrag + (size_t)kt * 512 + lane;
    #pragma unroll
    for (int ob = 0; ob < 8; ++ob) {
      short8 av = __builtin_bit_cast(short8, wk[ob * 64]);
      acc[ob] = __builtin_amdgcn_mfma_f32_16x16x32_bf16(av, bv, acc[ob], 0, 0, 0);
    }
  }
  #pragma unroll
  for (int ob = 0; ob < 8; ++ob) {
    #pragma unroll
    for (int r = 0; r < 4; ++r) {
      int o = ob * 16 + g * 4 + r;
      outb[(size_t)o * MM + m] = acc[ob][r] + bias[o];
    }
  }
}

// ---------------- GEMM2/3 (MFMA): X' = relu(bn(X)); C = W @ X' + bias ----------------
__global__ __launch_bounds__(256, 4) void gemm23_mfma(
    const float* __restrict__ inb, const float* __restrict__ scale,
    const float* __restrict__ shift, const uint4* __restrict__ wfrag,
    const float* __restrict__ bias, float* __restrict__ outb) {
  int t = threadIdx.x;
  int wid = t >> 6, lane = t & 63;
  int bid = blockIdx.x;
  bid = (bid & 7) * 128 + (bid >> 3);
  int m0 = bid * 64 + wid * 16;
  int cl = lane & 15, g = lane >> 4;
  int m  = m0 + cl;
  const float* src = inb + m;
  f32x4 acc[8] = {};
  for (int kt = 0; kt < 4; ++kt) {
    int kbase = kt * 32 + g * 8;
    short8 bv;
    #pragma unroll
    for (int j = 0; j < 8; ++j) {
      int c = kbase + j;
      float x = src[(size_t)c * MM];
      bv[j] = f2bf(fmaxf(fmaf(x, scale[c], shift[c]), 0.f));
    }
    const uint4* wk = wfrag + (size_t)kt * 512 + lane;
    #pragma unroll
    for (int ob = 0; ob < 8; ++ob) {
      short8 av = __builtin_bit_cast(short8, wk[ob * 64]);
      acc[ob] = __builtin_amdgcn_mfma_f32_16x16x32_bf16(av, bv, acc[ob], 0, 0, 0);
    }
  }
  #pragma unroll
  for (int ob = 0; ob < 8; ++ob) {
    #pragma unroll
    for (int r = 0; r < 4; ++r) {
      int o = ob * 16 + g * 4 + r;
      outb[(size_t)o * MM + m] = acc[ob][r] + bias[o];   // in-place safe: block writes only its own m-tile, after all its reads
    }
  }
}

// ---------------- per-channel sum/sumsq over [128][M] buffer ----------------
__global__ __launch_bounds__(256) void stats_k(const float* __restrict__ buf,
                                               float* __restrict__ gsum,
                                               float* __restrict__ gssq) {
  int o = blockIdx.x >> 3, chunk = blockIdx.x & 7;
  const float4* src = (const float4*)(buf + (size_t)o * MM + chunk * 8192);
  int t = threadIdx.x;
  float s = 0.f, q = 0.f;
  #pragma unroll
  for (int e = 0; e < 8; ++e) {
    float4 v = src[e * 256 + t];
    s += v.x + v.y + v.z + v.w;
    q += v.x*v.x + v.y*v.y + v.z*v.z + v.w*v.w;
  }
  #pragma unroll
  for (int off = 32; off; off >>= 1) { s += __shfl_down(s, off, 64); q += __shfl_down(q, off, 64); }
  __shared__ float ss[4], sq[4];
  if ((t & 63) == 0) { ss[t >> 6] = s; sq[t >> 6] = q; }
  __syncthreads();
  if (t == 0) {
    atomicAdd(&gsum[o], ss[0] + ss[1] + ss[2] + ss[3]);
    atomicAdd(&gssq[o], sq[0] + sq[1] + sq[2] + sq[3]);
  }
}

// ---------------- finalize BN stats -> scale/shift ----------------
__global__ void finalize_bn(const float* __restrict__ gsum, const float* __restrict__ gssq,
                            const float* __restrict__ g, const float* __restrict__ be,
                            float* __restrict__ scale, float* __restrict__ shift) {
  int c = threadIdx.x;
  const float invM = 1.0f / (float)MM;
  float mean = gsum[c] * invM;
  float var  = gssq[c] * invM - mean * mean;
  float rstd = rsqrtf(var + 1e-5f);
  float sc   = g[c] * rstd;
  scale[c] = sc;
  shift[c] = fmaf(-mean, sc, be[c]);
}

// ---------------- final: out[b][o][n] = relu(bn2(h2) + relu(bn0(x))) ----------------
__global__ __launch_bounds__(256) void final_kernel(
    const float* __restrict__ bufX, const float* __restrict__ bufH,
    const float* __restrict__ bnp, float* __restrict__ out) {
  int lin = blockIdx.x * 256 + threadIdx.x;     // over [128][M/4]
  int o = lin >> 14;
  int r = lin & 16383;
  int m = r * 4;
  int b = m >> 12;
  int n = m & (NN - 1);
  float s0 = bnp[o], t0 = bnp[128 + o], s2 = bnp[512 + o], t2 = bnp[640 + o];
  float4 x = *(const float4*)(bufX + (size_t)o * MM + m);
  float4 h = *(const float4*)(bufH + (size_t)o * MM + m);
  float4 y;
  y.x = fmaxf(fmaf(h.x, s2, t2) + fmaxf(fmaf(x.x, s0, t0), 0.f), 0.f);
  y.y = fmaxf(fmaf(h.y, s2, t2) + fmaxf(fmaf(x.y, s0, t0), 0.f), 0.f);
  y.z = fmaxf(fmaf(h.z, s2, t2) + fmaxf(fmaf(x.z, s0, t0), 0.f), 0.f);
  y.w = fmaxf(fmaf(h.w, s2, t2) + fmaxf(fmaf(x.w, s0, t0), 0.f), 0.f);
  *(float4*)(out + (size_t)b * CO * NN + (size_t)o * NN + n) = y;
}

extern "C" void kernel_launch(void* const* d_in, const int* in_sizes, int n_in,
                              void* d_out, int out_size, void* d_ws, size_t ws_size,
                              hipStream_t stream) {
  const float* xyz1    = (const float*)d_in[0];
  const float* xyz2    = (const float*)d_in[1];
  const float* points1 = (const float*)d_in[2];
  const float* points2 = (const float*)d_in[3];
  const float* fuse_w  = (const float*)d_in[4];
  const float* fuse_b  = (const float*)d_in[5];
  const float* fuse_g  = (const float*)d_in[6];
  const float* fuse_be = (const float*)d_in[7];
  const float* w1      = (const float*)d_in[8];
  const float* b1      = (const float*)d_in[9];
  const float* g1      = (const float*)d_in[10];
  const float* be1     = (const float*)d_in[11];
  const float* w2      = (const float*)d_in[12];
  const float* b2      = (const float*)d_in[13];
  const float* g2      = (const float*)d_in[14];
  const float* be2     = (const float*)d_in[15];

  char* ws = (char*)d_ws;
  size_t off = 0;
  auto alloc = [&](size_t bytes) -> void* {
    void* p = ws + off;
    off += (bytes + 255) & ~(size_t)255;
    return p;
  };
  int*   idx3  = (int*)  alloc((size_t)MM * 3 * 4);
  float* w3    = (float*)alloc((size_t)MM * 3 * 4);
  uint4* wf0   = (uint4*)alloc((size_t)(CIN/32) * 8 * 64 * 16);
  uint4* wf1   = (uint4*)alloc((size_t)(CO/32)  * 8 * 64 * 16);
  uint4* wf2   = (uint4*)alloc((size_t)(CO/32)  * 8 * 64 * 16);
  float* stats = (float*)alloc(6 * 128 * 4);  // gsum0,gssq0,gsum1,gssq1,gsum2,gssq2
  float* bnp   = (float*)alloc(6 * 128 * 4);  // scale0,shift0,scale1,shift1,scale2,shift2
  float* bufX  = (float*)alloc((size_t)MM * CO * 4);
  float* bufH  = (float*)alloc((size_t)MM * CO * 4);
  if (off > ws_size) return;

  hipMemsetAsync(stats, 0, 6 * 128 * 4, stream);
  arrange_w<<<(CIN/32)*8, 64, 0, stream>>>(fuse_w, wf0, CIN);
  arrange_w<<<(CO/32)*8,  64, 0, stream>>>(w1,     wf1, CO);
  arrange_w<<<(CO/32)*8,  64, 0, stream>>>(w2,     wf2, CO);
  top3_kernel<<<BB * (NN/256), 256, 0, stream>>>(xyz1, xyz2, idx3, w3);

  gemm1_mfma<<<MM/64, 256, 0, stream>>>(points1, points2, idx3, w3, wf0, fuse_b, bufX);
  stats_k<<<128*8, 256, 0, stream>>>(bufX, stats + 0, stats + 128);
  finalize_bn<<<1, 128, 0, stream>>>(stats + 0, stats + 128, fuse_g, fuse_be, bnp + 0, bnp + 128);

  gemm23_mfma<<<MM/64, 256, 0, stream>>>(bufX, bnp + 0, bnp + 128, wf1, b1, bufH);
  stats_k<<<128*8, 256, 0, stream>>>(bufH, stats + 256, stats + 384);
  finalize_bn<<<1, 128, 0, stream>>>(stats + 256, stats + 384, g1, be1, bnp + 256, bnp + 384);

  gemm23_mfma<<<MM/64, 256, 0, stream>>>(bufH, bnp + 256, bnp + 384, wf2, b2, bufH);
  stats_k<<<128*8, 256, 0, stream>>>(bufH, stats + 512, stats + 640);
  finalize_bn<<<1, 128, 0, stream>>>(stats + 512, stats + 640, g2, be2, bnp + 512, bnp + 640);

  final_kernel<<<(CO * (MM/4)) / 256, 256, 0, stream>>>(bufX, bufH, bnp, (float*)d_out);
}

// Round 4
// 299.038 us; speedup vs baseline: 1.5517x; 1.4711x over previous
//
#include <hip/hip_runtime.h>

#define BB   16
#define NN   4096
#define SS   1024
#define D1C  128
#define D2C  256
#define CIN  384
#define CO   128
#define MM   (BB*NN)   // 65536 rows

typedef __attribute__((ext_vector_type(8))) short short8;
typedef __attribute__((ext_vector_type(8))) unsigned short ushort8;
typedef __attribute__((ext_vector_type(4))) float f32x4;

__device__ __forceinline__ unsigned short f2bf(float f) {
  unsigned u = __builtin_bit_cast(unsigned, f);
  u += 0x7fffu + ((u >> 16) & 1u);           // RNE
  return (unsigned short)(u >> 16);
}
__device__ __forceinline__ float bf2f(unsigned short u) {
  unsigned x = ((unsigned)u) << 16;
  return __builtin_bit_cast(float, x);
}

// ---------------- arrange all three weights into per-lane MFMA A-fragments ----------------
// wf[(kt*8+ob)*64+lane] = 8 bf16 of W[o=ob*16+(lane&15)][k=kt*32+(lane>>4)*8 .. +7]
__global__ __launch_bounds__(64) void arrange_all(
    const float* __restrict__ w0, const float* __restrict__ w1, const float* __restrict__ w2,
    uint4* __restrict__ wf0, uint4* __restrict__ wf1, uint4* __restrict__ wf2) {
  int blk = blockIdx.x;
  const float* w; uint4* wf; int K; int local;
  if (blk < 96)       { w = w0; wf = wf0; K = CIN; local = blk; }
  else if (blk < 128) { w = w1; wf = wf1; K = CO;  local = blk - 96; }
  else                { w = w2; wf = wf2; K = CO;  local = blk - 128; }
  int lane = threadIdx.x;
  int id = local * 64 + lane;
  int ob = (id >> 6) & 7;
  int kt = id >> 9;
  int o = ob * 16 + (lane & 15);
  int k = kt * 32 + (lane >> 4) * 8;
  const float* src = w + (size_t)o * K + k;
  union { unsigned short u[8]; uint4 v; } p;
  #pragma unroll
  for (int j = 0; j < 8; ++j) p.u[j] = f2bf(src[j]);
  wf[id] = p.v;
}

// ---------------- transpose points2 [b][c][s] f32 -> p2t [b][s][c] bf16 ----------------
__global__ __launch_bounds__(256) void transp2(const float* __restrict__ p2,
                                               unsigned short* __restrict__ p2t) {
  int b  = blockIdx.x >> 6;
  int s0 = (blockIdx.x & 63) * 16;
  int c  = threadIdx.x;                       // 0..255
  const float* src = p2 + ((size_t)b * D2C + c) * SS + s0;
  float v[16];
  #pragma unroll
  for (int k = 0; k < 4; ++k) {
    float4 x = *(const float4*)(src + k * 4);
    v[k*4+0] = x.x; v[k*4+1] = x.y; v[k*4+2] = x.z; v[k*4+3] = x.w;
  }
  unsigned short* dst = p2t + ((size_t)b * SS + s0) * D2C + c;
  #pragma unroll
  for (int s = 0; s < 16; ++s) dst[(size_t)s * D2C] = f2bf(v[s]);
}

// ---------------- top-3 NN: 4 lanes per query point, shfl merge ----------------
#define INS(dd, ii) { if ((dd) < d2) { if ((dd) < d1) { if ((dd) < d0) { \
  d2=d1;i2=i1; d1=d0;i1=i0; d0=(dd);i0=(ii); } else { d2=d1;i2=i1; d1=(dd);i1=(ii); } } \
  else { d2=(dd);i2=(ii); } } }

__global__ __launch_bounds__(256) void top3_kernel(const float* __restrict__ xyz1,
                                                   const float* __restrict__ xyz2,
                                                   int* __restrict__ idx3,
                                                   float* __restrict__ w3) {
  __shared__ float4 sp[SS];                   // (x,y,z,|p|^2) 16KB
  int b  = blockIdx.x >> 6;
  int nb = (blockIdx.x & 63) * 64;
  int t  = threadIdx.x;
  const float* x2 = xyz2 + (size_t)b * SS * 3;
  for (int i = t; i < SS; i += 256) {
    float a = x2[i*3+0], c = x2[i*3+1], d = x2[i*3+2];
    sp[i] = make_float4(a, c, d, a*a + c*c + d*d);
  }
  __syncthreads();
  int nl = t >> 2, q = t & 3;
  int n  = nb + nl;
  size_t gm = (size_t)b * NN + n;
  float px = xyz1[gm*3+0], py = xyz1[gm*3+1], pz = xyz1[gm*3+2];
  float n1 = px*px + py*py + pz*pz;
  float d0 = 3.4e38f, d1 = 3.4e38f, d2 = 3.4e38f;
  int   i0 = 0, i1 = 0, i2 = 0;
  int sbase = q * 256;
  #pragma unroll 4
  for (int s = 0; s < 256; ++s) {
    float4 p = sp[sbase + s];
    float d = n1 + p.w - 2.0f * (px*p.x + py*p.y + pz*p.z);
    INS(d, sbase + s);
  }
  #pragma unroll
  for (int msk = 1; msk <= 2; msk <<= 1) {
    float e0 = __shfl_xor(d0, msk), e1 = __shfl_xor(d1, msk), e2 = __shfl_xor(d2, msk);
    int   j0 = __shfl_xor(i0, msk), j1 = __shfl_xor(i1, msk), j2 = __shfl_xor(i2, msk);
    INS(e0, j0); INS(e1, j1); INS(e2, j2);
  }
  if (q == 0) {
    float r0 = 1.0f/(d0 + 1e-8f), r1 = 1.0f/(d1 + 1e-8f), r2 = 1.0f/(d2 + 1e-8f);
    float inv = 1.0f/(r0 + r1 + r2);
    idx3[gm*3+0] = i0; idx3[gm*3+1] = i1; idx3[gm*3+2] = i2;
    w3  [gm*3+0] = r0*inv; w3[gm*3+1] = r1*inv; w3[gm*3+2] = r2*inv;
  }
}

// ---------------- GEMM1 (MFMA): C[o][m] = sum_k W[o][k]*feats[k][m] + bias; bf16 out + partial stats ----------------
__global__ __launch_bounds__(256, 4) void gemm1_mfma(
    const float* __restrict__ p1, const unsigned short* __restrict__ p2t,
    const int* __restrict__ idx3, const float* __restrict__ w3,
    const uint4* __restrict__ wfrag, const float* __restrict__ bias,
    unsigned short* __restrict__ outb, float* __restrict__ pblk) {
  __shared__ float sSum[128], sSsq[128];
  int t = threadIdx.x;
  int wid = t >> 6, lane = t & 63;
  if (t < 128) { sSum[t] = 0.f; sSsq[t] = 0.f; }
  int bid = blockIdx.x;
  bid = (bid & 7) * 128 + (bid >> 3);          // XCD-chunked swizzle (1024 % 8 == 0)
  int m0 = bid * 64 + wid * 16;
  int b  = m0 >> 12;
  int cl = lane & 15, g = lane >> 4;
  int m  = m0 + cl;
  int n  = m & (NN - 1);
  int i0 = idx3[(size_t)m*3+0], i1 = idx3[(size_t)m*3+1], i2 = idx3[(size_t)m*3+2];
  float wA = w3[(size_t)m*3+0], wB = w3[(size_t)m*3+1], wC = w3[(size_t)m*3+2];
  const unsigned short* r0 = p2t + ((size_t)b * SS + i0) * D2C;
  const unsigned short* r1 = p2t + ((size_t)b * SS + i1) * D2C;
  const unsigned short* r2 = p2t + ((size_t)b * SS + i2) * D2C;
  const float* p1b = p1 + (size_t)b * D1C * NN + n;
  f32x4 acc[8] = {};
  for (int kt = 0; kt < 12; ++kt) {
    short8 bv;
    if (kt < 4) {
      int kbase = kt * 32 + g * 8;
      #pragma unroll
      for (int j = 0; j < 8; ++j) bv[j] = (short)f2bf(p1b[(size_t)(kbase + j) * NN]);
    } else {
      int c0 = (kt - 4) * 32 + g * 8;
      ushort8 u0 = *(const ushort8*)(r0 + c0);
      ushort8 u1 = *(const ushort8*)(r1 + c0);
      ushort8 u2 = *(const ushort8*)(r2 + c0);
      #pragma unroll
      for (int j = 0; j < 8; ++j)
        bv[j] = (short)f2bf(wA*bf2f(u0[j]) + wB*bf2f(u1[j]) + wC*bf2f(u2[j]));
    }
    const uint4* wk = wfrag + (size_t)kt * 512 + lane;
    #pragma unroll
    for (int ob = 0; ob < 8; ++ob) {
      short8 av = __builtin_bit_cast(short8, wk[ob * 64]);
      acc[ob] = __builtin_amdgcn_mfma_f32_16x16x32_bf16(av, bv, acc[ob], 0, 0, 0);
    }
  }
  __syncthreads();
  #pragma unroll
  for (int ob = 0; ob < 8; ++ob) {
    #pragma unroll
    for (int r = 0; r < 4; ++r) {
      int o = ob * 16 + g * 4 + r;
      float v = acc[ob][r] + bias[o];
      outb[(size_t)o * MM + m] = f2bf(v);
      float s = v, q = v * v;
      #pragma unroll
      for (int off = 1; off < 16; off <<= 1) { s += __shfl_xor(s, off); q += __shfl_xor(q, off); }
      if (cl == 0) { atomicAdd(&sSum[o], s); atomicAdd(&sSsq[o], q); }
    }
  }
  __syncthreads();
  if (t < 128) {
    pblk[(size_t)blockIdx.x * 256 + t]       = sSum[t];
    pblk[(size_t)blockIdx.x * 256 + 128 + t] = sSsq[t];
  }
}

// ---------------- GEMM2/3 (MFMA): X' = relu(bn(X_bf16)); C = W @ X' + bias; bf16 out + partial stats ----------------
__global__ __launch_bounds__(256, 4) void gemm23_mfma(
    const unsigned short* __restrict__ inb, const float* __restrict__ scale,
    const float* __restrict__ shift, const uint4* __restrict__ wfrag,
    const float* __restrict__ bias, unsigned short* __restrict__ outb,
    float* __restrict__ pblk) {
  __shared__ float sSum[128], sSsq[128];
  int t = threadIdx.x;
  int wid = t >> 6, lane = t & 63;
  if (t < 128) { sSum[t] = 0.f; sSsq[t] = 0.f; }
  int bid = blockIdx.x;
  bid = (bid & 7) * 128 + (bid >> 3);
  int m0 = bid * 64 + wid * 16;
  int cl = lane & 15, g = lane >> 4;
  int m  = m0 + cl;
  const unsigned short* src = inb + m;
  f32x4 acc[8] = {};
  for (int kt = 0; kt < 4; ++kt) {
    int kbase = kt * 32 + g * 8;
    short8 bv;
    #pragma unroll
    for (int j = 0; j < 8; ++j) {
      int c = kbase + j;
      float x = bf2f(src[(size_t)c * MM]);
      bv[j] = (short)f2bf(fmaxf(fmaf(x, scale[c], shift[c]), 0.f));
    }
    const uint4* wk = wfrag + (size_t)kt * 512 + lane;
    #pragma unroll
    for (int ob = 0; ob < 8; ++ob) {
      short8 av = __builtin_bit_cast(short8, wk[ob * 64]);
      acc[ob] = __builtin_amdgcn_mfma_f32_16x16x32_bf16(av, bv, acc[ob], 0, 0, 0);
    }
  }
  __syncthreads();
  #pragma unroll
  for (int ob = 0; ob < 8; ++ob) {
    #pragma unroll
    for (int r = 0; r < 4; ++r) {
      int o = ob * 16 + g * 4 + r;
      float v = acc[ob][r] + bias[o];
      outb[(size_t)o * MM + m] = f2bf(v);
      float s = v, q = v * v;
      #pragma unroll
      for (int off = 1; off < 16; off <<= 1) { s += __shfl_xor(s, off); q += __shfl_xor(q, off); }
      if (cl == 0) { atomicAdd(&sSum[o], s); atomicAdd(&sSsq[o], q); }
    }
  }
  __syncthreads();
  if (t < 128) {
    pblk[(size_t)blockIdx.x * 256 + t]       = sSum[t];
    pblk[(size_t)blockIdx.x * 256 + 128 + t] = sSsq[t];
  }
}

// ---------------- reduce partials + finalize BN scale/shift ----------------
__global__ __launch_bounds__(256) void reduce_fin(const float* __restrict__ pblk,
                                                  const float* __restrict__ g,
                                                  const float* __restrict__ be,
                                                  float* __restrict__ scale,
                                                  float* __restrict__ shift) {
  int o = blockIdx.x, t = threadIdx.x;
  float s = 0.f, q = 0.f;
  #pragma unroll
  for (int it = 0; it < 4; ++it) {
    const float* p = pblk + (size_t)(it * 256 + t) * 256;
    s += p[o]; q += p[128 + o];
  }
  #pragma unroll
  for (int off = 32; off; off >>= 1) { s += __shfl_down(s, off, 64); q += __shfl_down(q, off, 64); }
  __shared__ float ls[4], lq[4];
  if ((t & 63) == 0) { ls[t >> 6] = s; lq[t >> 6] = q; }
  __syncthreads();
  if (t == 0) {
    float S = ls[0]+ls[1]+ls[2]+ls[3], Q = lq[0]+lq[1]+lq[2]+lq[3];
    const float invM = 1.0f / (float)MM;
    float mean = S * invM;
    float var  = Q * invM - mean * mean;
    float rstd = rsqrtf(var + 1e-5f);
    float sc   = g[o] * rstd;
    scale[o] = sc;
    shift[o] = fmaf(-mean, sc, be[o]);
  }
}

// ---------------- final: out[b][o][n] = relu(bn2(h2) + relu(bn0(x))) ----------------
__global__ __launch_bounds__(256) void final_kernel(
    const unsigned short* __restrict__ bufX, const unsigned short* __restrict__ bufH2,
    const float* __restrict__ bnp, float* __restrict__ out) {
  int lin = blockIdx.x * 256 + threadIdx.x;     // over [128][M/8]
  int o = lin >> 13;
  int r = lin & 8191;
  int m = r * 8;
  int b = m >> 12;
  int n = m & (NN - 1);
  float s0 = bnp[o], t0 = bnp[128 + o], s2 = bnp[512 + o], t2 = bnp[640 + o];
  ushort8 xu = *(const ushort8*)(bufX  + (size_t)o * MM + m);
  ushort8 hu = *(const ushort8*)(bufH2 + (size_t)o * MM + m);
  float y[8];
  #pragma unroll
  for (int j = 0; j < 8; ++j) {
    float x = bf2f(xu[j]), h = bf2f(hu[j]);
    y[j] = fmaxf(fmaf(h, s2, t2) + fmaxf(fmaf(x, s0, t0), 0.f), 0.f);
  }
  float* dst = out + (size_t)b * CO * NN + (size_t)o * NN + n;
  *(float4*)dst       = make_float4(y[0], y[1], y[2], y[3]);
  *(float4*)(dst + 4) = make_float4(y[4], y[5], y[6], y[7]);
}

extern "C" void kernel_launch(void* const* d_in, const int* in_sizes, int n_in,
                              void* d_out, int out_size, void* d_ws, size_t ws_size,
                              hipStream_t stream) {
  const float* xyz1    = (const float*)d_in[0];
  const float* xyz2    = (const float*)d_in[1];
  const float* points1 = (const float*)d_in[2];
  const float* points2 = (const float*)d_in[3];
  const float* fuse_w  = (const float*)d_in[4];
  const float* fuse_b  = (const float*)d_in[5];
  const float* fuse_g  = (const float*)d_in[6];
  const float* fuse_be = (const float*)d_in[7];
  const float* w1      = (const float*)d_in[8];
  const float* b1      = (const float*)d_in[9];
  const float* g1      = (const float*)d_in[10];
  const float* be1     = (const float*)d_in[11];
  const float* w2      = (const float*)d_in[12];
  const float* b2      = (const float*)d_in[13];
  const float* g2      = (const float*)d_in[14];
  const float* be2     = (const float*)d_in[15];

  char* ws = (char*)d_ws;
  size_t off = 0;
  auto alloc = [&](size_t bytes) -> void* {
    void* p = ws + off;
    off += (bytes + 255) & ~(size_t)255;
    return p;
  };
  int*            idx3 = (int*)           alloc((size_t)MM * 3 * 4);
  float*          w3   = (float*)         alloc((size_t)MM * 3 * 4);
  uint4*          wf0  = (uint4*)         alloc((size_t)96 * 64 * 16);
  uint4*          wf1  = (uint4*)         alloc((size_t)32 * 64 * 16);
  uint4*          wf2  = (uint4*)         alloc((size_t)32 * 64 * 16);
  float*          pblk = (float*)         alloc((size_t)1024 * 256 * 4);
  float*          bnp  = (float*)         alloc(6 * 128 * 4);
  unsigned short* p2t  = (unsigned short*)alloc((size_t)BB * SS * D2C * 2);
  unsigned short* bufX = (unsigned short*)alloc((size_t)MM * CO * 2);
  unsigned short* bufH = (unsigned short*)alloc((size_t)MM * CO * 2);
  unsigned short* bufH2= (unsigned short*)alloc((size_t)MM * CO * 2);
  if (off > ws_size) return;

  arrange_all<<<160, 64, 0, stream>>>(fuse_w, w1, w2, wf0, wf1, wf2);
  transp2<<<BB * 64, 256, 0, stream>>>(points2, p2t);
  top3_kernel<<<BB * 64, 256, 0, stream>>>(xyz1, xyz2, idx3, w3);

  gemm1_mfma<<<MM/64, 256, 0, stream>>>(points1, p2t, idx3, w3, wf0, fuse_b, bufX, pblk);
  reduce_fin<<<128, 256, 0, stream>>>(pblk, fuse_g, fuse_be, bnp + 0, bnp + 128);

  gemm23_mfma<<<MM/64, 256, 0, stream>>>(bufX, bnp + 0, bnp + 128, wf1, b1, bufH, pblk);
  reduce_fin<<<128, 256, 0, stream>>>(pblk, g1, be1, bnp + 256, bnp + 384);

  gemm23_mfma<<<MM/64, 256, 0, stream>>>(bufH, bnp + 256, bnp + 384, wf2, b2, bufH2, pblk);
  reduce_fin<<<128, 256, 0, stream>>>(pblk, g2, be2, bnp + 512, bnp + 640);

  final_kernel<<<(CO * (MM/8)) / 256, 256, 0, stream>>>(bufX, bufH2, bnp, (float*)d_out);
}

// Round 5
// 272.809 us; speedup vs baseline: 1.7009x; 1.0961x over previous
//
#include <hip/hip_runtime.h>

#define BB   16
#define NN   4096
#define SS   1024
#define D1C  128
#define D2C  256
#define CIN  384
#define CO   128
#define MM   (BB*NN)   // 65536 rows

typedef __attribute__((ext_vector_type(8))) short short8;
typedef __attribute__((ext_vector_type(8))) unsigned short ushort8;
typedef __attribute__((ext_vector_type(4))) float f32x4;

__device__ __forceinline__ unsigned short f2bf(float f) {
  unsigned u = __builtin_bit_cast(unsigned, f);
  u += 0x7fffu + ((u >> 16) & 1u);           // RNE
  return (unsigned short)(u >> 16);
}
__device__ __forceinline__ float bf2f(unsigned short u) {
  unsigned x = ((unsigned)u) << 16;
  return __builtin_bit_cast(float, x);
}
__device__ __forceinline__ unsigned cvt_pk(float lo, float hi) {
  unsigned r;
  asm("v_cvt_pk_bf16_f32 %0, %1, %2" : "=v"(r) : "v"(lo), "v"(hi));
  return r;
}
__device__ __forceinline__ ushort8 ld8(const unsigned short* p) {
  return *(const ushort8*)p;
}

// ---------------- arrange all three weights into per-lane MFMA A-fragments ----------------
// wf[(kt*8+ob)*64+lane] = 8 bf16 of W[o=ob*16+(lane&15)][k=kt*32+(lane>>4)*8 .. +7]
__global__ __launch_bounds__(64) void arrange_all(
    const float* __restrict__ w0, const float* __restrict__ w1, const float* __restrict__ w2,
    uint4* __restrict__ wf0, uint4* __restrict__ wf1, uint4* __restrict__ wf2) {
  int blk = blockIdx.x;
  const float* w; uint4* wf; int K; int local;
  if (blk < 96)       { w = w0; wf = wf0; K = CIN; local = blk; }
  else if (blk < 128) { w = w1; wf = wf1; K = CO;  local = blk - 96; }
  else                { w = w2; wf = wf2; K = CO;  local = blk - 128; }
  int lane = threadIdx.x;
  int id = local * 64 + lane;
  int ob = (id >> 6) & 7;
  int kt = id >> 9;
  int o = ob * 16 + (lane & 15);
  int k = kt * 32 + (lane >> 4) * 8;
  const float* src = w + (size_t)o * K + k;
  union { unsigned short u[8]; uint4 v; } p;
  #pragma unroll
  for (int j = 0; j < 8; ++j) p.u[j] = f2bf(src[j]);
  wf[id] = p.v;
}

// ---------------- transpose points2 [b][c][s] f32 -> p2t [b][s][c] bf16 ----------------
__global__ __launch_bounds__(256) void transp2(const float* __restrict__ p2,
                                               unsigned short* __restrict__ p2t) {
  int b  = blockIdx.x >> 6;
  int s0 = (blockIdx.x & 63) * 16;
  int c  = threadIdx.x;                       // 0..255
  const float* src = p2 + ((size_t)b * D2C + c) * SS + s0;
  float v[16];
  #pragma unroll
  for (int k = 0; k < 4; ++k) {
    float4 x = *(const float4*)(src + k * 4);
    v[k*4+0] = x.x; v[k*4+1] = x.y; v[k*4+2] = x.z; v[k*4+3] = x.w;
  }
  unsigned short* dst = p2t + ((size_t)b * SS + s0) * D2C + c;
  #pragma unroll
  for (int s = 0; s < 16; ++s) dst[(size_t)s * D2C] = f2bf(v[s]);
}

// ---------------- transpose points1 [b][c][n] f32 -> p1t [b][n][c] bf16 ----------------
__global__ __launch_bounds__(256) void transp1(const float* __restrict__ p1,
                                               unsigned short* __restrict__ p1t) {
  int b  = blockIdx.x >> 7;
  int n0 = (blockIdx.x & 127) * 32;
  int c  = threadIdx.x & 127;
  int nh = threadIdx.x >> 7;
  int n  = n0 + nh * 16;
  const float* src = p1 + ((size_t)b * D1C + c) * NN + n;
  float v[16];
  #pragma unroll
  for (int k = 0; k < 4; ++k) {
    float4 x = *(const float4*)(src + k * 4);
    v[k*4+0] = x.x; v[k*4+1] = x.y; v[k*4+2] = x.z; v[k*4+3] = x.w;
  }
  unsigned short* dst = p1t + ((size_t)b * NN + n) * D1C + c;
  #pragma unroll
  for (int s = 0; s < 16; ++s) dst[(size_t)s * D1C] = f2bf(v[s]);
}

// ---------------- top-3 NN: 4 lanes per query point, shfl merge ----------------
#define INS(dd, ii) { if ((dd) < d2) { if ((dd) < d1) { if ((dd) < d0) { \
  d2=d1;i2=i1; d1=d0;i1=i0; d0=(dd);i0=(ii); } else { d2=d1;i2=i1; d1=(dd);i1=(ii); } } \
  else { d2=(dd);i2=(ii); } } }

__global__ __launch_bounds__(256) void top3_kernel(const float* __restrict__ xyz1,
                                                   const float* __restrict__ xyz2,
                                                   int* __restrict__ idx3,
                                                   float* __restrict__ w3) {
  __shared__ float4 sp[SS];                   // (x,y,z,|p|^2) 16KB
  int b  = blockIdx.x >> 6;
  int nb = (blockIdx.x & 63) * 64;
  int t  = threadIdx.x;
  const float* x2 = xyz2 + (size_t)b * SS * 3;
  for (int i = t; i < SS; i += 256) {
    float a = x2[i*3+0], c = x2[i*3+1], d = x2[i*3+2];
    sp[i] = make_float4(a, c, d, a*a + c*c + d*d);
  }
  __syncthreads();
  int nl = t >> 2, q = t & 3;
  int n  = nb + nl;
  size_t gm = (size_t)b * NN + n;
  float px = xyz1[gm*3+0], py = xyz1[gm*3+1], pz = xyz1[gm*3+2];
  float n1 = px*px + py*py + pz*pz;
  float d0 = 3.4e38f, d1 = 3.4e38f, d2 = 3.4e38f;
  int   i0 = 0, i1 = 0, i2 = 0;
  int sbase = q * 256;
  #pragma unroll 4
  for (int s = 0; s < 256; ++s) {
    float4 p = sp[sbase + s];
    float d = n1 + p.w - 2.0f * (px*p.x + py*p.y + pz*p.z);
    INS(d, sbase + s);
  }
  #pragma unroll
  for (int msk = 1; msk <= 2; msk <<= 1) {
    float e0 = __shfl_xor(d0, msk), e1 = __shfl_xor(d1, msk), e2 = __shfl_xor(d2, msk);
    int   j0 = __shfl_xor(i0, msk), j1 = __shfl_xor(i1, msk), j2 = __shfl_xor(i2, msk);
    INS(e0, j0); INS(e1, j1); INS(e2, j2);
  }
  if (q == 0) {
    float r0 = 1.0f/(d0 + 1e-8f), r1 = 1.0f/(d1 + 1e-8f), r2 = 1.0f/(d2 + 1e-8f);
    float inv = 1.0f/(r0 + r1 + r2);
    idx3[gm*3+0] = i0; idx3[gm*3+1] = i1; idx3[gm*3+2] = i2;
    w3  [gm*3+0] = r0*inv; w3[gm*3+1] = r1*inv; w3[gm*3+2] = r2*inv;
  }
}

// ---------------- shared GEMM epilogue: acc -> LDS tile -> coalesced [m][c] store + stats ----------------
__device__ __forceinline__ void gemm_epilogue(
    f32x4 acc[8], const float* __restrict__ bias,
    unsigned short* __restrict__ outb, float* __restrict__ pblk,
    int m0b, int wid, int cl, int g, int t, int rawblk) {
  __shared__ unsigned short tile[64][136];    // pad: 272B row stride (16B-aligned)
  __shared__ float sS[256], sQ[256];
  #pragma unroll
  for (int ob = 0; ob < 8; ++ob) {
    float4 bs = *(const float4*)(bias + ob * 16 + g * 4);
    float v0 = acc[ob][0] + bs.x, v1 = acc[ob][1] + bs.y;
    float v2 = acc[ob][2] + bs.z, v3 = acc[ob][3] + bs.w;
    uint2 pk;
    pk.x = cvt_pk(v0, v1);
    pk.y = cvt_pk(v2, v3);
    *(uint2*)&tile[wid * 16 + cl][ob * 16 + g * 4] = pk;
  }
  __syncthreads();
  // per-channel partial stats from the bf16 tile
  int c = t & 127, half = t >> 7;
  float s = 0.f, q = 0.f;
  #pragma unroll
  for (int i = 0; i < 32; ++i) {
    float v = bf2f(tile[half * 32 + i][c]);
    s += v; q = fmaf(v, v, q);
  }
  sS[t] = s; sQ[t] = q;
  // coalesced global store of the tile
  int m_l = t >> 2, cq = (t & 3) * 32;
  unsigned short* gdst = outb + (size_t)(m0b + m_l) * CO + cq;
  #pragma unroll
  for (int qd = 0; qd < 4; ++qd)
    *(uint4*)(gdst + qd * 8) = *(const uint4*)&tile[m_l][cq + qd * 8];
  __syncthreads();
  if (t < 128) {
    pblk[(size_t)rawblk * 256 + t]       = sS[t] + sS[t + 128];
    pblk[(size_t)rawblk * 256 + 128 + t] = sQ[t] + sQ[t + 128];
  }
}

// ---------------- GEMM1 (MFMA): C[o][m], feats from p1t + 3-NN gather of p2t ----------------
__global__ __launch_bounds__(256, 4) void gemm1_mfma(
    const unsigned short* __restrict__ p1t, const unsigned short* __restrict__ p2t,
    const int* __restrict__ idx3, const float* __restrict__ w3,
    const uint4* __restrict__ wfrag, const float* __restrict__ bias,
    unsigned short* __restrict__ outb, float* __restrict__ pblk) {
  int t = threadIdx.x;
  int wid = t >> 6, lane = t & 63;
  int rawblk = blockIdx.x;
  int bid = (rawblk & 7) * 128 + (rawblk >> 3);   // XCD-chunked swizzle (1024 % 8 == 0)
  int m0b = bid * 64;
  int m0 = m0b + wid * 16;
  int b  = m0 >> 12;
  int cl = lane & 15, g = lane >> 4;
  int m  = m0 + cl;
  int i0 = idx3[(size_t)m*3+0], i1 = idx3[(size_t)m*3+1], i2 = idx3[(size_t)m*3+2];
  float wA = w3[(size_t)m*3+0], wB = w3[(size_t)m*3+1], wC = w3[(size_t)m*3+2];
  const unsigned short* r0 = p2t + ((size_t)b * SS + i0) * D2C + g * 8;
  const unsigned short* r1 = p2t + ((size_t)b * SS + i1) * D2C + g * 8;
  const unsigned short* r2 = p2t + ((size_t)b * SS + i2) * D2C + g * 8;
  const unsigned short* pr = p1t + (size_t)m * D1C + g * 8;

  // hoisted load batch 1: p1 tiles (already bf16) + gather kt 4..7
  ushort8 pt[4], ua[4][3];
  #pragma unroll
  for (int kt = 0; kt < 4; ++kt) pt[kt] = ld8(pr + kt * 32);
  #pragma unroll
  for (int q = 0; q < 4; ++q) {
    int c0 = q * 32;
    ua[q][0] = ld8(r0 + c0); ua[q][1] = ld8(r1 + c0); ua[q][2] = ld8(r2 + c0);
  }
  f32x4 acc[8] = {};
  // kt 0..3 : p1 path, zero conversion
  #pragma unroll
  for (int kt = 0; kt < 4; ++kt) {
    short8 bv = __builtin_bit_cast(short8, pt[kt]);
    const uint4* wk = wfrag + (size_t)kt * 512 + lane;
    #pragma unroll
    for (int ob = 0; ob < 8; ++ob)
      acc[ob] = __builtin_amdgcn_mfma_f32_16x16x32_bf16(
          __builtin_bit_cast(short8, wk[ob * 64]), bv, acc[ob], 0, 0, 0);
  }
  // kt 4..7 : gather batch 1
  #pragma unroll
  for (int q = 0; q < 4; ++q) {
    float f[8];
    #pragma unroll
    for (int j = 0; j < 8; ++j)
      f[j] = wA*bf2f(ua[q][0][j]) + wB*bf2f(ua[q][1][j]) + wC*bf2f(ua[q][2][j]);
    uint4 pk;
    pk.x = cvt_pk(f[0], f[1]); pk.y = cvt_pk(f[2], f[3]);
    pk.z = cvt_pk(f[4], f[5]); pk.w = cvt_pk(f[6], f[7]);
    short8 bv = __builtin_bit_cast(short8, pk);
    const uint4* wk = wfrag + (size_t)(4 + q) * 512 + lane;
    #pragma unroll
    for (int ob = 0; ob < 8; ++ob)
      acc[ob] = __builtin_amdgcn_mfma_f32_16x16x32_bf16(
          __builtin_bit_cast(short8, wk[ob * 64]), bv, acc[ob], 0, 0, 0);
  }
  __builtin_amdgcn_sched_barrier(0);   // keep batch-2 loads below (VGPR cap)
  // hoisted load batch 2: gather kt 8..11
  ushort8 ub[4][3];
  #pragma unroll
  for (int q = 0; q < 4; ++q) {
    int c0 = 128 + q * 32;
    ub[q][0] = ld8(r0 + c0); ub[q][1] = ld8(r1 + c0); ub[q][2] = ld8(r2 + c0);
  }
  #pragma unroll
  for (int q = 0; q < 4; ++q) {
    float f[8];
    #pragma unroll
    for (int j = 0; j < 8; ++j)
      f[j] = wA*bf2f(ub[q][0][j]) + wB*bf2f(ub[q][1][j]) + wC*bf2f(ub[q][2][j]);
    uint4 pk;
    pk.x = cvt_pk(f[0], f[1]); pk.y = cvt_pk(f[2], f[3]);
    pk.z = cvt_pk(f[4], f[5]); pk.w = cvt_pk(f[6], f[7]);
    short8 bv = __builtin_bit_cast(short8, pk);
    const uint4* wk = wfrag + (size_t)(8 + q) * 512 + lane;
    #pragma unroll
    for (int ob = 0; ob < 8; ++ob)
      acc[ob] = __builtin_amdgcn_mfma_f32_16x16x32_bf16(
          __builtin_bit_cast(short8, wk[ob * 64]), bv, acc[ob], 0, 0, 0);
  }
  gemm_epilogue(acc, bias, outb, pblk, m0b, wid, cl, g, t, rawblk);
}

// ---------------- GEMM2/3 (MFMA): X' = relu(bn(X[m][c])); C = W @ X' + bias ----------------
__global__ __launch_bounds__(256, 4) void gemm23_mfma(
    const unsigned short* __restrict__ inb, const float* __restrict__ scale,
    const float* __restrict__ shift, const uint4* __restrict__ wfrag,
    const float* __restrict__ bias, unsigned short* __restrict__ outb,
    float* __restrict__ pblk) {
  int t = threadIdx.x;
  int wid = t >> 6, lane = t & 63;
  int rawblk = blockIdx.x;
  int bid = (rawblk & 7) * 128 + (rawblk >> 3);
  int m0b = bid * 64;
  int m0 = m0b + wid * 16;
  int cl = lane & 15, g = lane >> 4;
  int m  = m0 + cl;
  const unsigned short* src = inb + (size_t)m * CO + g * 8;
  ushort8 xv[4];
  #pragma unroll
  for (int kt = 0; kt < 4; ++kt) xv[kt] = ld8(src + kt * 32);
  f32x4 acc[8] = {};
  #pragma unroll
  for (int kt = 0; kt < 4; ++kt) {
    int kb = kt * 32 + g * 8;
    float4 sa = *(const float4*)(scale + kb), sb = *(const float4*)(scale + kb + 4);
    float4 ha = *(const float4*)(shift + kb), hb = *(const float4*)(shift + kb + 4);
    float f[8];
    f[0] = fmaxf(fmaf(bf2f(xv[kt][0]), sa.x, ha.x), 0.f);
    f[1] = fmaxf(fmaf(bf2f(xv[kt][1]), sa.y, ha.y), 0.f);
    f[2] = fmaxf(fmaf(bf2f(xv[kt][2]), sa.z, ha.z), 0.f);
    f[3] = fmaxf(fmaf(bf2f(xv[kt][3]), sa.w, ha.w), 0.f);
    f[4] = fmaxf(fmaf(bf2f(xv[kt][4]), sb.x, hb.x), 0.f);
    f[5] = fmaxf(fmaf(bf2f(xv[kt][5]), sb.y, hb.y), 0.f);
    f[6] = fmaxf(fmaf(bf2f(xv[kt][6]), sb.z, hb.z), 0.f);
    f[7] = fmaxf(fmaf(bf2f(xv[kt][7]), sb.w, hb.w), 0.f);
    uint4 pk;
    pk.x = cvt_pk(f[0], f[1]); pk.y = cvt_pk(f[2], f[3]);
    pk.z = cvt_pk(f[4], f[5]); pk.w = cvt_pk(f[6], f[7]);
    short8 bv = __builtin_bit_cast(short8, pk);
    const uint4* wk = wfrag + (size_t)kt * 512 + lane;
    #pragma unroll
    for (int ob = 0; ob < 8; ++ob)
      acc[ob] = __builtin_amdgcn_mfma_f32_16x16x32_bf16(
          __builtin_bit_cast(short8, wk[ob * 64]), bv, acc[ob], 0, 0, 0);
  }
  gemm_epilogue(acc, bias, outb, pblk, m0b, wid, cl, g, t, rawblk);
}

// ---------------- reduce partials + finalize BN scale/shift ----------------
__global__ __launch_bounds__(256) void reduce_fin(const float* __restrict__ pblk,
                                                  const float* __restrict__ g,
                                                  const float* __restrict__ be,
                                                  float* __restrict__ scale,
                                                  float* __restrict__ shift) {
  int o = blockIdx.x, t = threadIdx.x;
  float s = 0.f, q = 0.f;
  #pragma unroll
  for (int it = 0; it < 4; ++it) {
    const float* p = pblk + (size_t)(it * 256 + t) * 256;
    s += p[o]; q += p[128 + o];
  }
  #pragma unroll
  for (int off = 32; off; off >>= 1) { s += __shfl_down(s, off, 64); q += __shfl_down(q, off, 64); }
  __shared__ float ls[4], lq[4];
  if ((t & 63) == 0) { ls[t >> 6] = s; lq[t >> 6] = q; }
  __syncthreads();
  if (t == 0) {
    float S = ls[0]+ls[1]+ls[2]+ls[3], Q = lq[0]+lq[1]+lq[2]+lq[3];
    const float invM = 1.0f / (float)MM;
    float mean = S * invM;
    float var  = Q * invM - mean * mean;
    float rstd = rsqrtf(var + 1e-5f);
    float sc   = g[o] * rstd;
    scale[o] = sc;
    shift[o] = fmaf(-mean, sc, be[o]);
  }
}

// ---------------- final: out[b][o][n] = relu(bn2(h2) + relu(bn0(x))), [m][c] -> [o][n] ----------------
__global__ __launch_bounds__(256) void final_kernel(
    const unsigned short* __restrict__ bufX, const unsigned short* __restrict__ bufH2,
    const float* __restrict__ bnp, float* __restrict__ out) {
  __shared__ float yt[128][33];               // [c][m_local], 16.9KB
  __shared__ float sb[512];                   // s0,t0,s2,t2
  int t = threadIdx.x;
  if (t < 128) {
    sb[t]       = bnp[t];
    sb[128 + t] = bnp[128 + t];
    sb[256 + t] = bnp[512 + t];
    sb[384 + t] = bnp[640 + t];
  }
  __syncthreads();
  int m0 = blockIdx.x * 32;
  int b  = m0 >> 12;
  int n0 = m0 & (NN - 1);
  int m_l = t >> 3;
  int cq  = (t & 7) * 16;
  size_t base = (size_t)(m0 + m_l) * CO + cq;
  ushort8 xu0 = ld8(bufX  + base), xu1 = ld8(bufX  + base + 8);
  ushort8 hu0 = ld8(bufH2 + base), hu1 = ld8(bufH2 + base + 8);
  #pragma unroll
  for (int j = 0; j < 16; ++j) {
    int c = cq + j;
    float x = bf2f(j < 8 ? xu0[j & 7] : xu1[j & 7]);
    float h = bf2f(j < 8 ? hu0[j & 7] : hu1[j & 7]);
    float y = fmaxf(fmaf(h, sb[256 + c], sb[384 + c]) +
                    fmaxf(fmaf(x, sb[c], sb[128 + c]), 0.f), 0.f);
    yt[c][m_l] = y;
  }
  __syncthreads();
  int o  = t >> 1;
  int nh = (t & 1) * 16;
  float* dst = out + (size_t)b * CO * NN + (size_t)o * NN + n0 + nh;
  #pragma unroll
  for (int qd = 0; qd < 4; ++qd)
    *(float4*)(dst + qd * 4) = make_float4(yt[o][nh + qd*4 + 0], yt[o][nh + qd*4 + 1],
                                           yt[o][nh + qd*4 + 2], yt[o][nh + qd*4 + 3]);
}

extern "C" void kernel_launch(void* const* d_in, const int* in_sizes, int n_in,
                              void* d_out, int out_size, void* d_ws, size_t ws_size,
                              hipStream_t stream) {
  const float* xyz1    = (const float*)d_in[0];
  const float* xyz2    = (const float*)d_in[1];
  const float* points1 = (const float*)d_in[2];
  const float* points2 = (const float*)d_in[3];
  const float* fuse_w  = (const float*)d_in[4];
  const float* fuse_b  = (const float*)d_in[5];
  const float* fuse_g  = (const float*)d_in[6];
  const float* fuse_be = (const float*)d_in[7];
  const float* w1      = (const float*)d_in[8];
  const float* b1      = (const float*)d_in[9];
  const float* g1      = (const float*)d_in[10];
  const float* be1     = (const float*)d_in[11];
  const float* w2      = (const float*)d_in[12];
  const float* b2      = (const float*)d_in[13];
  const float* g2      = (const float*)d_in[14];
  const float* be2     = (const float*)d_in[15];

  char* ws = (char*)d_ws;
  size_t off = 0;
  auto alloc = [&](size_t bytes) -> void* {
    void* p = ws + off;
    off += (bytes + 255) & ~(size_t)255;
    return p;
  };
  int*            idx3 = (int*)           alloc((size_t)MM * 3 * 4);
  float*          w3   = (float*)         alloc((size_t)MM * 3 * 4);
  uint4*          wf0  = (uint4*)         alloc((size_t)96 * 64 * 16);
  uint4*          wf1  = (uint4*)         alloc((size_t)32 * 64 * 16);
  uint4*          wf2  = (uint4*)         alloc((size_t)32 * 64 * 16);
  float*          pblk = (float*)         alloc((size_t)1024 * 256 * 4);
  float*          bnp  = (float*)         alloc(6 * 128 * 4);
  unsigned short* p2t  = (unsigned short*)alloc((size_t)BB * SS * D2C * 2);
  unsigned short* p1t  = (unsigned short*)alloc((size_t)MM * D1C * 2);
  unsigned short* bufX = (unsigned short*)alloc((size_t)MM * CO * 2);
  unsigned short* bufH = (unsigned short*)alloc((size_t)MM * CO * 2);
  unsigned short* bufH2= (unsigned short*)alloc((size_t)MM * CO * 2);
  if (off > ws_size) return;

  arrange_all<<<160, 64, 0, stream>>>(fuse_w, w1, w2, wf0, wf1, wf2);
  transp2<<<BB * 64, 256, 0, stream>>>(points2, p2t);
  transp1<<<BB * 128, 256, 0, stream>>>(points1, p1t);
  top3_kernel<<<BB * 64, 256, 0, stream>>>(xyz1, xyz2, idx3, w3);

  gemm1_mfma<<<MM/64, 256, 0, stream>>>(p1t, p2t, idx3, w3, wf0, fuse_b, bufX, pblk);
  reduce_fin<<<128, 256, 0, stream>>>(pblk, fuse_g, fuse_be, bnp + 0, bnp + 128);

  gemm23_mfma<<<MM/64, 256, 0, stream>>>(bufX, bnp + 0, bnp + 128, wf1, b1, bufH, pblk);
  reduce_fin<<<128, 256, 0, stream>>>(pblk, g1, be1, bnp + 256, bnp + 384);

  gemm23_mfma<<<MM/64, 256, 0, stream>>>(bufH, bnp + 256, bnp + 384, wf2, b2, bufH2, pblk);
  reduce_fin<<<128, 256, 0, stream>>>(pblk, g2, be2, bnp + 512, bnp + 640);

  final_kernel<<<MM/32, 256, 0, stream>>>(bufX, bufH2, bnp, (float*)d_out);
}

// Round 6
// 263.859 us; speedup vs baseline: 1.7586x; 1.0339x over previous
//
#include <hip/hip_runtime.h>

#define BB   16
#define NN   4096
#define SS   1024
#define D1C  128
#define D2C  256
#define CIN  384
#define CO   128
#define MM   (BB*NN)   // 65536 rows

typedef __attribute__((ext_vector_type(8))) short short8;
typedef __attribute__((ext_vector_type(8))) unsigned short ushort8;
typedef __attribute__((ext_vector_type(4))) float f32x4;

__device__ __forceinline__ unsigned short f2bf(float f) {
  unsigned u = __builtin_bit_cast(unsigned, f);
  u += 0x7fffu + ((u >> 16) & 1u);           // RNE
  return (unsigned short)(u >> 16);
}
__device__ __forceinline__ float bf2f(unsigned short u) {
  unsigned x = ((unsigned)u) << 16;
  return __builtin_bit_cast(float, x);
}
__device__ __forceinline__ unsigned cvt_pk(float lo, float hi) {
  unsigned r;
  asm("v_cvt_pk_bf16_f32 %0, %1, %2" : "=v"(r) : "v"(lo), "v"(hi));
  return r;
}
__device__ __forceinline__ ushort8 ld8(const unsigned short* p) {
  return *(const ushort8*)p;
}

// ---------------- arrange all three weights into per-lane MFMA A-fragments ----------------
// wf[(kt*8+ob)*64+lane] = 8 bf16 of W[o=ob*16+(lane&15)][k=kt*32+(lane>>4)*8 .. +7]
__global__ __launch_bounds__(64) void arrange_all(
    const float* __restrict__ w0, const float* __restrict__ w1, const float* __restrict__ w2,
    uint4* __restrict__ wf0, uint4* __restrict__ wf1, uint4* __restrict__ wf2) {
  int blk = blockIdx.x;
  const float* w; uint4* wf; int K; int local;
  if (blk < 96)       { w = w0; wf = wf0; K = CIN; local = blk; }
  else if (blk < 128) { w = w1; wf = wf1; K = CO;  local = blk - 96; }
  else                { w = w2; wf = wf2; K = CO;  local = blk - 128; }
  int lane = threadIdx.x;
  int id = local * 64 + lane;
  int ob = (id >> 6) & 7;
  int kt = id >> 9;
  int o = ob * 16 + (lane & 15);
  int k = kt * 32 + (lane >> 4) * 8;
  const float* src = w + (size_t)o * K + k;
  union { unsigned short u[8]; uint4 v; } p;
  #pragma unroll
  for (int j = 0; j < 8; ++j) p.u[j] = f2bf(src[j]);
  wf[id] = p.v;
}

// ---------------- transpose points2 [b][c][s] f32 -> p2t [b][s][c] bf16 ----------------
__global__ __launch_bounds__(256) void transp2(const float* __restrict__ p2,
                                               unsigned short* __restrict__ p2t) {
  int b  = blockIdx.x >> 6;
  int s0 = (blockIdx.x & 63) * 16;
  int c  = threadIdx.x;                       // 0..255
  const float* src = p2 + ((size_t)b * D2C + c) * SS + s0;
  float v[16];
  #pragma unroll
  for (int k = 0; k < 4; ++k) {
    float4 x = *(const float4*)(src + k * 4);
    v[k*4+0] = x.x; v[k*4+1] = x.y; v[k*4+2] = x.z; v[k*4+3] = x.w;
  }
  unsigned short* dst = p2t + ((size_t)b * SS + s0) * D2C + c;
  #pragma unroll
  for (int s = 0; s < 16; ++s) dst[(size_t)s * D2C] = f2bf(v[s]);
}

// ---------------- transpose points1 [b][c][n] f32 -> p1t [b][n][c] bf16 ----------------
__global__ __launch_bounds__(256) void transp1(const float* __restrict__ p1,
                                               unsigned short* __restrict__ p1t) {
  int b  = blockIdx.x >> 7;
  int n0 = (blockIdx.x & 127) * 32;
  int c  = threadIdx.x & 127;
  int nh = threadIdx.x >> 7;
  int n  = n0 + nh * 16;
  const float* src = p1 + ((size_t)b * D1C + c) * NN + n;
  float v[16];
  #pragma unroll
  for (int k = 0; k < 4; ++k) {
    float4 x = *(const float4*)(src + k * 4);
    v[k*4+0] = x.x; v[k*4+1] = x.y; v[k*4+2] = x.z; v[k*4+3] = x.w;
  }
  unsigned short* dst = p1t + ((size_t)b * NN + n) * D1C + c;
  #pragma unroll
  for (int s = 0; s < 16; ++s) dst[(size_t)s * D1C] = f2bf(v[s]);
}

// ---------------- top-3 NN: 8 lanes per query point, padded LDS octants, med3 updates ----------------
#define INS(dd, ii) { if ((dd) < d2) { if ((dd) < d1) { if ((dd) < d0) { \
  d2=d1;i2=i1; d1=d0;i1=i0; d0=(dd);i0=(ii); } else { d2=d1;i2=i1; d1=(dd);i1=(ii); } } \
  else { d2=(dd);i2=(ii); } } }

__global__ __launch_bounds__(256) void top3_kernel(const float* __restrict__ xyz1,
                                                   const float* __restrict__ xyz2,
                                                   int* __restrict__ idx3,
                                                   float* __restrict__ w3) {
  // 8 octants of 128 points, stride 129 float4 (2064B) => ds_read_b128 bank-conflict-free
  __shared__ float4 sp[8 * 129 - 1];          // 16496 B
  int b  = blockIdx.x >> 7;                   // 128 blocks/batch, 32 points each
  int nb = (blockIdx.x & 127) * 32;
  int t  = threadIdx.x;
  const float* x2 = xyz2 + (size_t)b * SS * 3;
  for (int i = t; i < SS; i += 256) {
    float a = x2[i*3+0], c = x2[i*3+1], d = x2[i*3+2];
    sp[(i >> 7) * 129 + (i & 127)] = make_float4(-2.f*a, -2.f*c, -2.f*d, a*a + c*c + d*d);
  }
  __syncthreads();
  int nl = t >> 3, q = t & 7;
  int n  = nb + nl;
  size_t gm = (size_t)b * NN + n;
  float px = xyz1[gm*3+0], py = xyz1[gm*3+1], pz = xyz1[gm*3+2];
  float d0 = 3.4e38f, d1 = 3.4e38f, d2 = 3.4e38f;
  int   i0 = 0, i1 = 0, i2 = 0;
  const float4* myq = sp + q * 129;
  int ibase = q * 128;
  #pragma unroll 4
  for (int s = 0; s < 128; ++s) {
    float4 p = myq[s];
    // scan key omits the per-query |x1|^2 (constant offset, order-invariant)
    float d = fmaf(px, p.x, fmaf(py, p.y, fmaf(pz, p.z, p.w)));
    int i = ibase + s;
    bool c0 = d < d0, c1 = d < d1, c2 = d < d2;
    i2 = c2 ? (c1 ? i1 : i) : i2;
    i1 = c1 ? (c0 ? i0 : i) : i1;
    i0 = c0 ? i : i0;
    d2 = __builtin_amdgcn_fmed3f(d1, d2, d);
    d1 = __builtin_amdgcn_fmed3f(d0, d1, d);
    d0 = fminf(d0, d);
  }
  #pragma unroll
  for (int msk = 1; msk <= 4; msk <<= 1) {
    float e0 = __shfl_xor(d0, msk), e1 = __shfl_xor(d1, msk), e2 = __shfl_xor(d2, msk);
    int   j0 = __shfl_xor(i0, msk), j1 = __shfl_xor(i1, msk), j2 = __shfl_xor(i2, msk);
    INS(e0, j0); INS(e1, j1); INS(e2, j2);
  }
  if (q == 0) {
    float n1 = px*px + py*py + pz*pz;
    float r0 = 1.0f/(d0 + n1 + 1e-8f), r1 = 1.0f/(d1 + n1 + 1e-8f), r2 = 1.0f/(d2 + n1 + 1e-8f);
    float inv = 1.0f/(r0 + r1 + r2);
    idx3[gm*3+0] = i0; idx3[gm*3+1] = i1; idx3[gm*3+2] = i2;
    w3  [gm*3+0] = r0*inv; w3[gm*3+1] = r1*inv; w3[gm*3+2] = r2*inv;
  }
}

// ---------------- shared GEMM epilogue: acc -> LDS tile -> coalesced [m][c] store + stats ----------------
__device__ __forceinline__ void gemm_epilogue(
    f32x4 acc[8], const float* __restrict__ bias,
    unsigned short* __restrict__ outb, float* __restrict__ pblk,
    int m0b, int wid, int cl, int g, int t, int rawblk) {
  __shared__ unsigned short tile[64][136];    // pad: 272B row stride (16B-aligned)
  __shared__ float sS[256], sQ[256];
  #pragma unroll
  for (int ob = 0; ob < 8; ++ob) {
    float4 bs = *(const float4*)(bias + ob * 16 + g * 4);
    float v0 = acc[ob][0] + bs.x, v1 = acc[ob][1] + bs.y;
    float v2 = acc[ob][2] + bs.z, v3 = acc[ob][3] + bs.w;
    uint2 pk;
    pk.x = cvt_pk(v0, v1);
    pk.y = cvt_pk(v2, v3);
    *(uint2*)&tile[wid * 16 + cl][ob * 16 + g * 4] = pk;
  }
  __syncthreads();
  // per-channel partial stats from the bf16 tile
  int c = t & 127, half = t >> 7;
  float s = 0.f, q = 0.f;
  #pragma unroll
  for (int i = 0; i < 32; ++i) {
    float v = bf2f(tile[half * 32 + i][c]);
    s += v; q = fmaf(v, v, q);
  }
  sS[t] = s; sQ[t] = q;
  // coalesced global store of the tile
  int m_l = t >> 2, cq = (t & 3) * 32;
  unsigned short* gdst = outb + (size_t)(m0b + m_l) * CO + cq;
  #pragma unroll
  for (int qd = 0; qd < 4; ++qd)
    *(uint4*)(gdst + qd * 8) = *(const uint4*)&tile[m_l][cq + qd * 8];
  __syncthreads();
  if (t < 128) {
    pblk[(size_t)rawblk * 256 + t]       = sS[t] + sS[t + 128];
    pblk[(size_t)rawblk * 256 + 128 + t] = sQ[t] + sQ[t + 128];
  }
}

// ---------------- GEMM1 (MFMA): C[o][m], feats from p1t + 3-NN gather of p2t ----------------
__global__ __launch_bounds__(256, 4) void gemm1_mfma(
    const unsigned short* __restrict__ p1t, const unsigned short* __restrict__ p2t,
    const int* __restrict__ idx3, const float* __restrict__ w3,
    const uint4* __restrict__ wfrag, const float* __restrict__ bias,
    unsigned short* __restrict__ outb, float* __restrict__ pblk) {
  int t = threadIdx.x;
  int wid = t >> 6, lane = t & 63;
  int rawblk = blockIdx.x;
  int bid = (rawblk & 7) * 128 + (rawblk >> 3);   // XCD-chunked swizzle (1024 % 8 == 0)
  int m0b = bid * 64;
  int m0 = m0b + wid * 16;
  int b  = m0 >> 12;
  int cl = lane & 15, g = lane >> 4;
  int m  = m0 + cl;
  int i0 = idx3[(size_t)m*3+0], i1 = idx3[(size_t)m*3+1], i2 = idx3[(size_t)m*3+2];
  float wA = w3[(size_t)m*3+0], wB = w3[(size_t)m*3+1], wC = w3[(size_t)m*3+2];
  const unsigned short* r0 = p2t + ((size_t)b * SS + i0) * D2C + g * 8;
  const unsigned short* r1 = p2t + ((size_t)b * SS + i1) * D2C + g * 8;
  const unsigned short* r2 = p2t + ((size_t)b * SS + i2) * D2C + g * 8;
  const unsigned short* pr = p1t + (size_t)m * D1C + g * 8;

  // hoisted load batch 1: p1 tiles (already bf16) + gather kt 4..7
  ushort8 pt[4], ua[4][3];
  #pragma unroll
  for (int kt = 0; kt < 4; ++kt) pt[kt] = ld8(pr + kt * 32);
  #pragma unroll
  for (int q = 0; q < 4; ++q) {
    int c0 = q * 32;
    ua[q][0] = ld8(r0 + c0); ua[q][1] = ld8(r1 + c0); ua[q][2] = ld8(r2 + c0);
  }
  f32x4 acc[8] = {};
  // kt 0..3 : p1 path, zero conversion
  #pragma unroll
  for (int kt = 0; kt < 4; ++kt) {
    short8 bv = __builtin_bit_cast(short8, pt[kt]);
    const uint4* wk = wfrag + (size_t)kt * 512 + lane;
    #pragma unroll
    for (int ob = 0; ob < 8; ++ob)
      acc[ob] = __builtin_amdgcn_mfma_f32_16x16x32_bf16(
          __builtin_bit_cast(short8, wk[ob * 64]), bv, acc[ob], 0, 0, 0);
  }
  // kt 4..7 : gather batch 1
  #pragma unroll
  for (int q = 0; q < 4; ++q) {
    float f[8];
    #pragma unroll
    for (int j = 0; j < 8; ++j)
      f[j] = wA*bf2f(ua[q][0][j]) + wB*bf2f(ua[q][1][j]) + wC*bf2f(ua[q][2][j]);
    uint4 pk;
    pk.x = cvt_pk(f[0], f[1]); pk.y = cvt_pk(f[2], f[3]);
    pk.z = cvt_pk(f[4], f[5]); pk.w = cvt_pk(f[6], f[7]);
    short8 bv = __builtin_bit_cast(short8, pk);
    const uint4* wk = wfrag + (size_t)(4 + q) * 512 + lane;
    #pragma unroll
    for (int ob = 0; ob < 8; ++ob)
      acc[ob] = __builtin_amdgcn_mfma_f32_16x16x32_bf16(
          __builtin_bit_cast(short8, wk[ob * 64]), bv, acc[ob], 0, 0, 0);
  }
  __builtin_amdgcn_sched_barrier(0);   // keep batch-2 loads below (VGPR cap)
  // hoisted load batch 2: gather kt 8..11
  ushort8 ub[4][3];
  #pragma unroll
  for (int q = 0; q < 4; ++q) {
    int c0 = 128 + q * 32;
    ub[q][0] = ld8(r0 + c0); ub[q][1] = ld8(r1 + c0); ub[q][2] = ld8(r2 + c0);
  }
  #pragma unroll
  for (int q = 0; q < 4; ++q) {
    float f[8];
    #pragma unroll
    for (int j = 0; j < 8; ++j)
      f[j] = wA*bf2f(ub[q][0][j]) + wB*bf2f(ub[q][1][j]) + wC*bf2f(ub[q][2][j]);
    uint4 pk;
    pk.x = cvt_pk(f[0], f[1]); pk.y = cvt_pk(f[2], f[3]);
    pk.z = cvt_pk(f[4], f[5]); pk.w = cvt_pk(f[6], f[7]);
    short8 bv = __builtin_bit_cast(short8, pk);
    const uint4* wk = wfrag + (size_t)(8 + q) * 512 + lane;
    #pragma unroll
    for (int ob = 0; ob < 8; ++ob)
      acc[ob] = __builtin_amdgcn_mfma_f32_16x16x32_bf16(
          __builtin_bit_cast(short8, wk[ob * 64]), bv, acc[ob], 0, 0, 0);
  }
  gemm_epilogue(acc, bias, outb, pblk, m0b, wid, cl, g, t, rawblk);
}

// ---------------- GEMM2/3 (MFMA): X' = relu(bn(X[m][c])); C = W @ X' + bias ----------------
__global__ __launch_bounds__(256, 4) void gemm23_mfma(
    const unsigned short* __restrict__ inb, const float* __restrict__ scale,
    const float* __restrict__ shift, const uint4* __restrict__ wfrag,
    const float* __restrict__ bias, unsigned short* __restrict__ outb,
    float* __restrict__ pblk) {
  int t = threadIdx.x;
  int wid = t >> 6, lane = t & 63;
  int rawblk = blockIdx.x;
  int bid = (rawblk & 7) * 128 + (rawblk >> 3);
  int m0b = bid * 64;
  int m0 = m0b + wid * 16;
  int cl = lane & 15, g = lane >> 4;
  int m  = m0 + cl;
  const unsigned short* src = inb + (size_t)m * CO + g * 8;
  ushort8 xv[4];
  #pragma unroll
  for (int kt = 0; kt < 4; ++kt) xv[kt] = ld8(src + kt * 32);
  f32x4 acc[8] = {};
  #pragma unroll
  for (int kt = 0; kt < 4; ++kt) {
    int kb = kt * 32 + g * 8;
    float4 sa = *(const float4*)(scale + kb), sb = *(const float4*)(scale + kb + 4);
    float4 ha = *(const float4*)(shift + kb), hb = *(const float4*)(shift + kb + 4);
    float f[8];
    f[0] = fmaxf(fmaf(bf2f(xv[kt][0]), sa.x, ha.x), 0.f);
    f[1] = fmaxf(fmaf(bf2f(xv[kt][1]), sa.y, ha.y), 0.f);
    f[2] = fmaxf(fmaf(bf2f(xv[kt][2]), sa.z, ha.z), 0.f);
    f[3] = fmaxf(fmaf(bf2f(xv[kt][3]), sa.w, ha.w), 0.f);
    f[4] = fmaxf(fmaf(bf2f(xv[kt][4]), sb.x, hb.x), 0.f);
    f[5] = fmaxf(fmaf(bf2f(xv[kt][5]), sb.y, hb.y), 0.f);
    f[6] = fmaxf(fmaf(bf2f(xv[kt][6]), sb.z, hb.z), 0.f);
    f[7] = fmaxf(fmaf(bf2f(xv[kt][7]), sb.w, hb.w), 0.f);
    uint4 pk;
    pk.x = cvt_pk(f[0], f[1]); pk.y = cvt_pk(f[2], f[3]);
    pk.z = cvt_pk(f[4], f[5]); pk.w = cvt_pk(f[6], f[7]);
    short8 bv = __builtin_bit_cast(short8, pk);
    const uint4* wk = wfrag + (size_t)kt * 512 + lane;
    #pragma unroll
    for (int ob = 0; ob < 8; ++ob)
      acc[ob] = __builtin_amdgcn_mfma_f32_16x16x32_bf16(
          __builtin_bit_cast(short8, wk[ob * 64]), bv, acc[ob], 0, 0, 0);
  }
  gemm_epilogue(acc, bias, outb, pblk, m0b, wid, cl, g, t, rawblk);
}

// ---------------- reduce partials + finalize BN scale/shift ----------------
__global__ __launch_bounds__(256) void reduce_fin(const float* __restrict__ pblk,
                                                  const float* __restrict__ g,
                                                  const float* __restrict__ be,
                                                  float* __restrict__ scale,
                                                  float* __restrict__ shift) {
  int o = blockIdx.x, t = threadIdx.x;
  float s = 0.f, q = 0.f;
  #pragma unroll
  for (int it = 0; it < 4; ++it) {
    const float* p = pblk + (size_t)(it * 256 + t) * 256;
    s += p[o]; q += p[128 + o];
  }
  #pragma unroll
  for (int off = 32; off; off >>= 1) { s += __shfl_down(s, off, 64); q += __shfl_down(q, off, 64); }
  __shared__ float ls[4], lq[4];
  if ((t & 63) == 0) { ls[t >> 6] = s; lq[t >> 6] = q; }
  __syncthreads();
  if (t == 0) {
    float S = ls[0]+ls[1]+ls[2]+ls[3], Q = lq[0]+lq[1]+lq[2]+lq[3];
    const float invM = 1.0f / (float)MM;
    float mean = S * invM;
    float var  = Q * invM - mean * mean;
    float rstd = rsqrtf(var + 1e-5f);
    float sc   = g[o] * rstd;
    scale[o] = sc;
    shift[o] = fmaf(-mean, sc, be[o]);
  }
}

// ---------------- final: out[b][o][n] = relu(bn2(h2) + relu(bn0(x))), [m][c] -> [o][n] ----------------
__global__ __launch_bounds__(256) void final_kernel(
    const unsigned short* __restrict__ bufX, const unsigned short* __restrict__ bufH2,
    const float* __restrict__ bnp, float* __restrict__ out) {
  __shared__ float yt[128][33];               // [c][m_local], 16.9KB
  __shared__ float sb[512];                   // s0,t0,s2,t2
  int t = threadIdx.x;
  if (t < 128) {
    sb[t]       = bnp[t];
    sb[128 + t] = bnp[128 + t];
    sb[256 + t] = bnp[512 + t];
    sb[384 + t] = bnp[640 + t];
  }
  __syncthreads();
  int m0 = blockIdx.x * 32;
  int b  = m0 >> 12;
  int n0 = m0 & (NN - 1);
  int m_l = t >> 3;
  int cq  = (t & 7) * 16;
  size_t base = (size_t)(m0 + m_l) * CO + cq;
  ushort8 xu0 = ld8(bufX  + base), xu1 = ld8(bufX  + base + 8);
  ushort8 hu0 = ld8(bufH2 + base), hu1 = ld8(bufH2 + base + 8);
  #pragma unroll
  for (int j = 0; j < 16; ++j) {
    int c = cq + j;
    float x = bf2f(j < 8 ? xu0[j & 7] : xu1[j & 7]);
    float h = bf2f(j < 8 ? hu0[j & 7] : hu1[j & 7]);
    float y = fmaxf(fmaf(h, sb[256 + c], sb[384 + c]) +
                    fmaxf(fmaf(x, sb[c], sb[128 + c]), 0.f), 0.f);
    yt[c][m_l] = y;
  }
  __syncthreads();
  int o  = t >> 1;
  int nh = (t & 1) * 16;
  float* dst = out + (size_t)b * CO * NN + (size_t)o * NN + n0 + nh;
  #pragma unroll
  for (int qd = 0; qd < 4; ++qd)
    *(float4*)(dst + qd * 4) = make_float4(yt[o][nh + qd*4 + 0], yt[o][nh + qd*4 + 1],
                                           yt[o][nh + qd*4 + 2], yt[o][nh + qd*4 + 3]);
}

extern "C" void kernel_launch(void* const* d_in, const int* in_sizes, int n_in,
                              void* d_out, int out_size, void* d_ws, size_t ws_size,
                              hipStream_t stream) {
  const float* xyz1    = (const float*)d_in[0];
  const float* xyz2    = (const float*)d_in[1];
  const float* points1 = (const float*)d_in[2];
  const float* points2 = (const float*)d_in[3];
  const float* fuse_w  = (const float*)d_in[4];
  const float* fuse_b  = (const float*)d_in[5];
  const float* fuse_g  = (const float*)d_in[6];
  const float* fuse_be = (const float*)d_in[7];
  const float* w1      = (const float*)d_in[8];
  const float* b1      = (const float*)d_in[9];
  const float* g1      = (const float*)d_in[10];
  const float* be1     = (const float*)d_in[11];
  const float* w2      = (const float*)d_in[12];
  const float* b2      = (const float*)d_in[13];
  const float* g2      = (const float*)d_in[14];
  const float* be2     = (const float*)d_in[15];

  char* ws = (char*)d_ws;
  size_t off = 0;
  auto alloc = [&](size_t bytes) -> void* {
    void* p = ws + off;
    off += (bytes + 255) & ~(size_t)255;
    return p;
  };
  int*            idx3 = (int*)           alloc((size_t)MM * 3 * 4);
  float*          w3   = (float*)         alloc((size_t)MM * 3 * 4);
  uint4*          wf0  = (uint4*)         alloc((size_t)96 * 64 * 16);
  uint4*          wf1  = (uint4*)         alloc((size_t)32 * 64 * 16);
  uint4*          wf2  = (uint4*)         alloc((size_t)32 * 64 * 16);
  float*          pblk = (float*)         alloc((size_t)1024 * 256 * 4);
  float*          bnp  = (float*)         alloc(6 * 128 * 4);
  unsigned short* p2t  = (unsigned short*)alloc((size_t)BB * SS * D2C * 2);
  unsigned short* p1t  = (unsigned short*)alloc((size_t)MM * D1C * 2);
  unsigned short* bufX = (unsigned short*)alloc((size_t)MM * CO * 2);
  unsigned short* bufH = (unsigned short*)alloc((size_t)MM * CO * 2);
  unsigned short* bufH2= (unsigned short*)alloc((size_t)MM * CO * 2);
  if (off > ws_size) return;

  arrange_all<<<160, 64, 0, stream>>>(fuse_w, w1, w2, wf0, wf1, wf2);
  transp2<<<BB * 64, 256, 0, stream>>>(points2, p2t);
  transp1<<<BB * 128, 256, 0, stream>>>(points1, p1t);
  top3_kernel<<<MM/32, 256, 0, stream>>>(xyz1, xyz2, idx3, w3);

  gemm1_mfma<<<MM/64, 256, 0, stream>>>(p1t, p2t, idx3, w3, wf0, fuse_b, bufX, pblk);
  reduce_fin<<<128, 256, 0, stream>>>(pblk, fuse_g, fuse_be, bnp + 0, bnp + 128);

  gemm23_mfma<<<MM/64, 256, 0, stream>>>(bufX, bnp + 0, bnp + 128, wf1, b1, bufH, pblk);
  reduce_fin<<<128, 256, 0, stream>>>(pblk, g1, be1, bnp + 256, bnp + 384);

  gemm23_mfma<<<MM/64, 256, 0, stream>>>(bufH, bnp + 256, bnp + 384, wf2, b2, bufH2, pblk);
  reduce_fin<<<128, 256, 0, stream>>>(pblk, g2, be2, bnp + 512, bnp + 640);

  final_kernel<<<MM/32, 256, 0, stream>>>(bufX, bufH2, bnp, (float*)d_out);
}